// Round 14
// baseline (190.661 us; speedup 1.0000x reference)
//
#include <hip/hip_runtime.h>
#include <hip/hip_bf16.h>

#define B_ 8
#define S_ 2048
#define E_ 128
#define CC_ 256
#define H_ 256
#define NH_ 8
#define HD_ 32
#define KW_ 7

typedef __attribute__((ext_vector_type(8))) short bf16x8;
typedef __attribute__((ext_vector_type(4))) float f32x4;
typedef __attribute__((ext_vector_type(16))) float f32x16;

// fold 1/sqrt(HD) * log2(e) into Q so attention works in exp2 domain
#define QSCALE_ (0.17677669529663687f * 1.4426950408889634f)
#define CPEN_   0.7213475204444817f   /* 0.5 * log2(e) */

static __device__ __forceinline__ unsigned short f2bf(float f) {
    __hip_bfloat16 h = __float2bfloat16(f);
    return *(unsigned short*)&h;
}
static __device__ __forceinline__ float bf2f(unsigned short u) {
    __hip_bfloat16 h = *(__hip_bfloat16*)&u;
    return __bfloat162float(h);
}
// v_permlane32_swap: newA = [A.lo | B.lo], newB = [A.hi | B.hi]
static __device__ __forceinline__ void perm32swap(unsigned& a, unsigned& b) {
    asm volatile("s_nop 1\n\tv_permlane32_swap_b32 %0, %1" : "+v"(a), "+v"(b));
}

// ---------------------------------------------------------------------------
// Merged prep: weight reorders + penalty/ctab/lenv. One launch. (unchanged)
// ---------------------------------------------------------------------------
__global__ __launch_bounds__(256) void prep_kernel(
    const float* __restrict__ cw, const float* __restrict__ wq,
    const float* __restrict__ wk, const float* __restrict__ wv,
    const float* __restrict__ fw, const void* __restrict__ mask,
    const float* __restrict__ gamma_p, const float* __restrict__ std_p,
    unsigned short* __restrict__ wre2, unsigned short* __restrict__ wqkv2,
    unsigned short* __restrict__ wf2, float* __restrict__ ctab,
    int* __restrict__ lenv)
{
    __shared__ int cnt[256];
    const int blk = blockIdx.x, tid = threadIdx.x;

    if (blk < 896) {                       // conv weights
        int i = blk * 256 + tid;
        int kl = i & 31, cc = (i >> 5) & 255, eb = (i >> 13) & 3, kk = i >> 15;
        wre2[i] = f2bf(cw[cc * (E_ * KW_) + (eb * 32 + kl) * KW_ + kk]);
    } else if (blk < 1664) {               // qkv weights
        int i = (blk - 896) * 256 + tid;
        int kl = i & 31, col = (i >> 5) & 255, kb = (i >> 13) & 7, m = i >> 16;
        const float* W = (m == 0) ? wq : (m == 1) ? wk : wv;
        wqkv2[i] = f2bf(W[(kb * 32 + kl) * H_ + col]);
    } else if (blk < 1920) {               // fc weights
        int i = (blk - 1664) * 256 + tid;
        int kl = i & 31, col = (i >> 5) & 255, kb = i >> 13;
        wf2[i] = f2bf(fw[(kb * 32 + kl) * CC_ + col]);
    } else {                               // penalty -> ctab + lenv
        int b = blk - 1920;

        uint32_t w0 = ((const uint32_t*)mask)[0];
        int mode = 0;
        if (w0 == 0x01010101u) mode = 1;
        else if (w0 == 0x3F803F80u) mode = 2;
        else if (w0 == 0x3F800000u) mode = 3;

        int c = 0;
        for (int s = tid; s < S_; s += 256) {
            bool vv;
            size_t i = (size_t)b * S_ + s;
            if (mode == 0)      vv = ((const int*)mask)[i] != 0;
            else if (mode == 1) vv = ((const unsigned char*)mask)[i] != 0;
            else if (mode == 2) vv = (((const unsigned short*)mask)[i] & 0x7FFFu) != 0;
            else                vv = ((const float*)mask)[i] != 0.f;
            c += vv ? 1 : 0;
        }
        cnt[tid] = c;
        __syncthreads();
        for (int off = 128; off > 0; off >>= 1) {
            if (tid < off) cnt[tid] += cnt[tid + off];
            __syncthreads();
        }
        int L = cnt[0];
        if (tid == 0) lenv[b] = L;

        float Lf = (float)L;
        float gamma = gamma_p[0];
        float sd = std_p[0];
        sd = fminf(fmaxf(sd, 0.01f), 0.5f);
        float scale = expf(gamma) - 1.f;
        float inv2s2 = 1.f / (2.f * sd * sd);
        float* row0 = ctab + (size_t)b * 2 * S_;
        float* row1 = row0 + S_;
        for (int s = tid; s < S_; s += 256) {
            float np = (s + 1.f) / (Lf + 1.f);
            float e = np - 0.5f;
            float base = expf(-(e * e) * inv2s2);
            bool vkk = s < L;
            row0[s] = vkk ? 0.f : -1e10f;
            row1[s] = vkk ? (-CPEN_ * base * scale) : -1e10f;
        }
    }
}

// ---------------------------------------------------------------------------
// Fused conv1d + QKV (unchanged)
// ---------------------------------------------------------------------------
__global__ __launch_bounds__(256) void front_kernel(
    const float* __restrict__ x, const unsigned short* __restrict__ wre2,
    const float* __restrict__ cb, const unsigned short* __restrict__ wqkv2,
    const float* __restrict__ bq, const float* __restrict__ bk,
    const float* __restrict__ bv, unsigned short* __restrict__ hb,
    unsigned short* __restrict__ qo, unsigned short* __restrict__ ko,
    unsigned short* __restrict__ vo)
{
    __shared__ __align__(16) char smem[64 * 264 * 2];   // 33792 B
    short (*xl)[136] = (short(*)[136])smem;             // 70x136 (19040 B)
    short (*Al)[264] = (short(*)[264])smem;             // 64x264 overlay

    const int tid = threadIdx.x, wave = tid >> 6, lane = tid & 63;
    const int l15 = lane & 15, l4 = lane >> 4;
    const int s0 = blockIdx.x * 64, b = blockIdx.y;

    // ---- stage x (f32 -> bf16) ----
    for (int idx = tid; idx < 70 * 32; idx += 256) {
        int row = idx >> 5, c4 = idx & 31;
        int pos = s0 - 3 + row;
        float4 v = {0.f, 0.f, 0.f, 0.f};
        if (pos >= 0 && pos < S_)
            v = *(const float4*)(x + ((size_t)b * S_ + pos) * E_ + c4 * 4);
        short* p = &xl[row][c4 * 4];
        p[0] = (short)f2bf(v.x); p[1] = (short)f2bf(v.y);
        p[2] = (short)f2bf(v.z); p[3] = (short)f2bf(v.w);
    }
    __syncthreads();

    // ---- conv: 7 shifted GEMMs ----
    f32x4 acc[4][4];
#pragma unroll
    for (int i = 0; i < 4; i++)
#pragma unroll
        for (int j = 0; j < 4; j++) acc[i][j] = (f32x4){0.f, 0.f, 0.f, 0.f};

#pragma unroll 1
    for (int kk = 0; kk < KW_; kk++) {
#pragma unroll
        for (int eb = 0; eb < 4; eb++) {
            const unsigned short* wp =
                wre2 + (((size_t)(kk * 4 + eb) * 256 + wave * 64 + l15) * 32) + l4 * 8;
            bf16x8 af[4], bfr[4];
#pragma unroll
            for (int ct = 0; ct < 4; ct++)
                bfr[ct] = *(const bf16x8*)(wp + ct * 512);
#pragma unroll
            for (int rt = 0; rt < 4; rt++)
                af[rt] = *(const bf16x8*)(&xl[rt * 16 + l15 + kk][eb * 32 + l4 * 8]);
#pragma unroll
            for (int rt = 0; rt < 4; rt++)
#pragma unroll
                for (int ct = 0; ct < 4; ct++)
                    acc[rt][ct] = __builtin_amdgcn_mfma_f32_16x16x32_bf16(
                        af[rt], bfr[ct], acc[rt][ct], 0, 0, 0);
        }
    }
    __syncthreads();   // all waves done reading xl -> safe to overlay Al

    // ---- epilogue: bias + relu -> Al (bf16) ----
#pragma unroll
    for (int ct = 0; ct < 4; ct++) {
        int col = wave * 64 + ct * 16 + l15;
        float bias = cb[col];
#pragma unroll
        for (int rt = 0; rt < 4; rt++)
#pragma unroll
            for (int r = 0; r < 4; r++) {
                float v0 = acc[rt][ct][r] + bias;
                v0 = v0 > 0.f ? v0 : 0.f;
                Al[rt * 16 + l4 * 4 + r][col] = (short)f2bf(v0);
            }
    }
    __syncthreads();

    // ---- copy h tile to global (coalesced) ----
    for (int idx = tid; idx < 64 * 32; idx += 256) {
        int row = idx >> 5, c8 = idx & 31;
        *(bf16x8*)(hb + ((size_t)b * S_ + s0 + row) * CC_ + c8 * 8) =
            *(const bf16x8*)(&Al[row][c8 * 8]);
    }

    // ---- QKV GEMMs from Al ----
#pragma unroll 1
    for (int m = 0; m < 3; m++) {
        f32x4 qacc[4][4];
#pragma unroll
        for (int i = 0; i < 4; i++)
#pragma unroll
            for (int j = 0; j < 4; j++) qacc[i][j] = (f32x4){0.f, 0.f, 0.f, 0.f};

#pragma unroll 1
        for (int kb8 = 0; kb8 < 8; kb8++) {
            const unsigned short* wp =
                wqkv2 + (((size_t)(m * 8 + kb8) * 256 + wave * 64 + l15) * 32) + l4 * 8;
            bf16x8 af[4], bfr[4];
#pragma unroll
            for (int ct = 0; ct < 4; ct++)
                bfr[ct] = *(const bf16x8*)(wp + ct * 512);
#pragma unroll
            for (int rt = 0; rt < 4; rt++)
                af[rt] = *(const bf16x8*)(&Al[rt * 16 + l15][kb8 * 32 + l4 * 8]);
#pragma unroll
            for (int rt = 0; rt < 4; rt++)
#pragma unroll
                for (int ct = 0; ct < 4; ct++)
                    qacc[rt][ct] = __builtin_amdgcn_mfma_f32_16x16x32_bf16(
                        af[rt], bfr[ct], qacc[rt][ct], 0, 0, 0);
        }

        const float* bias_p = (m == 0) ? bq : (m == 1) ? bk : bv;
        unsigned short* O = (m == 0) ? qo : (m == 1) ? ko : vo;
        const float oscale = (m == 0) ? QSCALE_ : 1.f;
#pragma unroll
        for (int ct = 0; ct < 4; ct++) {
            int col = wave * 64 + ct * 16 + l15;
            float bias = bias_p[col];
            int n = col >> 5, d = col & 31;
#pragma unroll
            for (int rt = 0; rt < 4; rt++)
#pragma unroll
                for (int r = 0; r < 4; r++) {
                    int row = s0 + rt * 16 + l4 * 4 + r;
                    O[(((size_t)b * NH_ + n) * S_ + row) * HD_ + d] =
                        f2bf((qacc[rt][ct][r] + bias) * oscale);
                }
        }
    }
}

// ---------------------------------------------------------------------------
// MFMA flash attention v11: KV tile 64 (LDS 39.9KB -> 20.5KB, 4 -> 7
// blocks/CU) for occupancy. Internals otherwise = v10: Σ-via-MFMA,
// wave-uniform m_r==0 fast path, lane-local max, permlane P, setprio,
// double-buffered 1-barrier-per-tile staging, round-7 grid.
// ---------------------------------------------------------------------------
__global__ __launch_bounds__(256) void attn_mfma_kernel(
    const unsigned short* __restrict__ q, const unsigned short* __restrict__ k,
    const unsigned short* __restrict__ v, const float* __restrict__ ctab,
    const int* __restrict__ lenv, unsigned short* __restrict__ ctxb)
{
    __shared__ short Kt[2][64][40];
    __shared__ short Vt[2][32][72];
    __shared__ __align__(16) float ctC[2][2][64];   // [buf][mask | mask+pen][key]

    const int tid = threadIdx.x;
    const int wave = tid >> 6, lane = tid & 63;
    const int r31 = lane & 31, hi = lane >> 5;
    const int hi8 = hi * 8, hi4 = hi * 4;

    // round-7 grid: qt fastest (blockIdx.x), n, b
    const int qt = blockIdx.x, n = blockIdx.y, b = blockIdx.z;
    const int qrow = qt * 128 + wave * 32 + r31;
    const int L = lenv[b];
    const int nt = (L + 63) >> 6;

    const size_t head = ((size_t)b * NH_ + n) * S_;
    const unsigned short* qbase = q + head * HD_;
    const unsigned short* kbase = k + head * HD_;
    const unsigned short* vbase = v + head * HD_;
    const float* ct0 = ctab + (size_t)b * 2 * S_;
    const float* ct1 = ct0 + S_;

    bf16x8 qf0 = *(const bf16x8*)(qbase + (size_t)qrow * HD_ + hi8);
    bf16x8 qf1 = *(const bf16x8*)(qbase + (size_t)qrow * HD_ + 16 + hi8);
    const int crow = (qrow < L) ? 1 : 0;

    // constant 1.0-bf16 A-fragment for the sum-MFMA
    bf16x8 ones;
#pragma unroll
    for (int i = 0; i < 8; i++) ones[i] = (short)0x3F80;

    f32x16 acc, acc_l;
#pragma unroll
    for (int r = 0; r < 16; r++) { acc[r] = 0.f; acc_l[r] = 0.f; }
    float m_r = 0.f;   // scores are O(1); defer threshold 8 keeps m_r == 0 a.e.

    // staging: 256 threads, one K bf16x8 + one V bf16x8 each (64 keys x 32 d)
    const int krow = tid >> 2, kch = (tid & 3) * 8;
    const int d7x2 = 2 * (r31 & 7);
    const int vc = krow >> 3, vk7 = krow & 7;

    bf16x8 kreg, va;
    float c0r = 0.f, c1r = 0.f;

    // ---- prologue: stage tile 0 ----
    kreg = *(const bf16x8*)(kbase + (size_t)krow * HD_ + kch);
    va   = *(const bf16x8*)(vbase + (size_t)krow * HD_ + kch);
    if (tid < 64) { c0r = ct0[tid]; c1r = ct1[tid]; }
    {
        *(bf16x8*)(&Kt[0][krow][kch]) = kreg;
#pragma unroll
        for (int i = 0; i < 8; i++) {
            int d0 = kch + i;
            Vt[0][d0][(((vc - 2 * (d0 & 7)) & 7) << 3) + vk7] = va[i];
        }
        if (tid < 64) { ctC[0][0][tid] = c0r; ctC[0][1][tid] = c1r; }
    }
    __syncthreads();

#pragma unroll 1
    for (int t = 0; t < nt; t++) {
        const int cur = t & 1;
        const int knext = (t + 1) << 6;
        const bool more = (t + 1 < nt);

        // ---- ISSUE next tile's global loads (K, V, ct) ----
        if (more) {
            kreg = *(const bf16x8*)(kbase + (size_t)(knext + krow) * HD_ + kch);
            va   = *(const bf16x8*)(vbase + (size_t)(knext + krow) * HD_ + kch);
            if (tid < 64) { c0r = ct0[knext + tid]; c1r = ct1[knext + tid]; }
        }

        // ---- QK^T: colterm (and -m_r when nonzero) folded into C ----
        __builtin_amdgcn_s_setprio(1);
        f32x16 sc[2];
        if (__all(m_r == 0.f)) {
#pragma unroll
            for (int t4 = 0; t4 < 2; t4++) {
                bf16x8 kf0 = *(const bf16x8*)(&Kt[cur][t4 * 32 + r31][hi8]);
                bf16x8 kf1 = *(const bf16x8*)(&Kt[cur][t4 * 32 + r31][16 + hi8]);
                f32x16 c0;
#pragma unroll
                for (int g = 0; g < 4; g++) {
                    f32x4 cp = *(const f32x4*)(&ctC[cur][crow][t4 * 32 + g * 8 + hi4]);
#pragma unroll
                    for (int j = 0; j < 4; j++) c0[g * 4 + j] = cp[j];
                }
                f32x16 s1 = __builtin_amdgcn_mfma_f32_32x32x16_bf16(kf0, qf0, c0, 0, 0, 0);
                sc[t4] = __builtin_amdgcn_mfma_f32_32x32x16_bf16(kf1, qf1, s1, 0, 0, 0);
            }
        } else {
#pragma unroll
            for (int t4 = 0; t4 < 2; t4++) {
                bf16x8 kf0 = *(const bf16x8*)(&Kt[cur][t4 * 32 + r31][hi8]);
                bf16x8 kf1 = *(const bf16x8*)(&Kt[cur][t4 * 32 + r31][16 + hi8]);
                f32x16 c0;
#pragma unroll
                for (int g = 0; g < 4; g++) {
                    f32x4 cp = *(const f32x4*)(&ctC[cur][crow][t4 * 32 + g * 8 + hi4]);
#pragma unroll
                    for (int j = 0; j < 4; j++) c0[g * 4 + j] = cp[j] - m_r;
                }
                f32x16 s1 = __builtin_amdgcn_mfma_f32_32x32x16_bf16(kf0, qf0, c0, 0, 0, 0);
                sc[t4] = __builtin_amdgcn_mfma_f32_32x32x16_bf16(kf1, qf1, s1, 0, 0, 0);
            }
        }
        __builtin_amdgcn_s_setprio(0);

        // ---- row max: 4 parallel chains, max3-fusable; lane-local only ----
        float mxa[4];
#pragma unroll
        for (int g = 0; g < 4; g++) mxa[g] = -1e30f;
#pragma unroll
        for (int t4 = 0; t4 < 2; t4++)
#pragma unroll
            for (int g = 0; g < 4; g++)
                mxa[g] = fmaxf(fmaxf(fmaxf(mxa[g], sc[t4][g * 4]),
                                     fmaxf(sc[t4][g * 4 + 1], sc[t4][g * 4 + 2])),
                               sc[t4][g * 4 + 3]);
        float pmx = fmaxf(fmaxf(mxa[0], mxa[1]), fmaxf(mxa[2], mxa[3]));

        // ---- defer-max: rare rescale path only (shfl inside) ----
        if (!__all(pmx <= 8.f)) {
            pmx = fmaxf(pmx, __shfl_xor(pmx, 32, 64));
            float d = fmaxf(pmx, 0.f);
            float alpha = exp2f(-d);
            m_r += d;
#pragma unroll
            for (int t4 = 0; t4 < 2; t4++)
#pragma unroll
                for (int r = 0; r < 16; r++) sc[t4][r] -= d;
#pragma unroll
            for (int r = 0; r < 16; r++) acc[r] *= alpha;
            acc_l[0] *= alpha;   // only element 0 is ever read
        }

        // ---- p = exp2(s), pack to bf16 + permlane (no sum pass) ----
        unsigned pk[2][8];
#pragma unroll
        for (int t4 = 0; t4 < 2; t4++) {
            unsigned U[8];
#pragma unroll
            for (int j = 0; j < 8; j++) {
                float pa = exp2f(sc[t4][2 * j]);
                float pb = exp2f(sc[t4][2 * j + 1]);
                U[j] = (unsigned)f2bf(pa) | ((unsigned)f2bf(pb) << 16);
            }
            perm32swap(U[0], U[2]);
            perm32swap(U[1], U[3]);
            perm32swap(U[4], U[6]);
            perm32swap(U[5], U[7]);
            pk[t4][0] = U[0]; pk[t4][1] = U[1]; pk[t4][2] = U[2]; pk[t4][3] = U[3];
            pk[t4][4] = U[4]; pk[t4][5] = U[5]; pk[t4][6] = U[6]; pk[t4][7] = U[7];
        }

        // ---- PV + sum-MFMA (denominator on the matrix pipe) ----
        __builtin_amdgcn_s_setprio(1);
#pragma unroll
        for (int t4 = 0; t4 < 2; t4++) {
            union { unsigned u[4]; bf16x8 v8; } pb0, pb1;
            pb0.u[0] = pk[t4][0]; pb0.u[1] = pk[t4][1];
            pb0.u[2] = pk[t4][2]; pb0.u[3] = pk[t4][3];
            pb1.u[0] = pk[t4][4]; pb1.u[1] = pk[t4][5];
            pb1.u[2] = pk[t4][6]; pb1.u[3] = pk[t4][7];
            int c0i = t4 * 4 + hi, c1i = t4 * 4 + 2 + hi;
            bf16x8 vf0 = *(const bf16x8*)(&Vt[cur][r31][((c0i - d7x2) & 7) << 3]);
            bf16x8 vf1 = *(const bf16x8*)(&Vt[cur][r31][((c1i - d7x2) & 7) << 3]);
            acc   = __builtin_amdgcn_mfma_f32_32x32x16_bf16(vf0, pb0.v8, acc, 0, 0, 0);
            acc_l = __builtin_amdgcn_mfma_f32_32x32x16_bf16(ones, pb0.v8, acc_l, 0, 0, 0);
            acc   = __builtin_amdgcn_mfma_f32_32x32x16_bf16(vf1, pb1.v8, acc, 0, 0, 0);
            acc_l = __builtin_amdgcn_mfma_f32_32x32x16_bf16(ones, pb1.v8, acc_l, 0, 0, 0);
        }
        __builtin_amdgcn_s_setprio(0);

        // ---- WRITE next tile, single barrier ----
        if (more) {
            const int nxt = cur ^ 1;
            *(bf16x8*)(&Kt[nxt][krow][kch]) = kreg;
#pragma unroll
            for (int i = 0; i < 8; i++) {
                int d0 = kch + i;
                Vt[nxt][d0][(((vc - 2 * (d0 & 7)) & 7) << 3) + vk7] = va[i];
            }
            if (tid < 64) { ctC[nxt][0][tid] = c0r; ctC[nxt][1][tid] = c1r; }
            __syncthreads();
        }
    }

    // epilogue: out[d][q] -> ctx row q; denominator from acc_l[0]
    float inv = 1.f / acc_l[0];
    size_t obase = ((size_t)b * S_ + qrow) * H_ + n * HD_;
#pragma unroll
    for (int g = 0; g < 4; g++)
#pragma unroll
        for (int w = 0; w < 2; w++) {
            unsigned uo = (unsigned)f2bf(acc[g * 4 + w * 2] * inv) |
                          ((unsigned)f2bf(acc[g * 4 + w * 2 + 1] * inv) << 16);
            int d = 8 * g + hi4 + 2 * w;
            *(unsigned*)(ctxb + obase + d) = uo;
        }
}

// ---------------------------------------------------------------------------
// FC GEMM + residual + LayerNorm fused. B direct from global; zero barriers.
// ---------------------------------------------------------------------------
__global__ __launch_bounds__(256) void fc_ln_mfma_kernel(
    const unsigned short* __restrict__ ctxb, const unsigned short* __restrict__ hb,
    const unsigned short* __restrict__ wf2, const float* __restrict__ fb,
    const float* __restrict__ g, const float* __restrict__ bbias,
    float* __restrict__ out)
{
    const int tid = threadIdx.x, wave = tid >> 6, lane = tid & 63;
    const int l15 = lane & 15, l4 = lane >> 4;
    const int s0 = blockIdx.x * 64, b = blockIdx.y;
    const int arow = s0 + wave * 16 + l15;

    bf16x8 af[8];
#pragma unroll
    for (int kb = 0; kb < 8; kb++)
        af[kb] = *(const bf16x8*)(ctxb + (size_t)((size_t)b * S_ + arow) * H_ + kb * 32 + l4 * 8);

    f32x4 acc[16];
#pragma unroll
    for (int ct = 0; ct < 16; ct++) acc[ct] = (f32x4){0.f, 0.f, 0.f, 0.f};

#pragma unroll 1
    for (int kb = 0; kb < 8; kb++) {
        const unsigned short* wp = wf2 + ((size_t)kb * 256 + l15) * 32 + l4 * 8;
#pragma unroll
        for (int ct = 0; ct < 16; ct++) {
            bf16x8 bfr = *(const bf16x8*)(wp + ct * 512);
            acc[ct] = __builtin_amdgcn_mfma_f32_16x16x32_bf16(af[kb], bfr, acc[ct], 0, 0, 0);
        }
    }

    float fbias[16];
#pragma unroll
    for (int ct = 0; ct < 16; ct++) fbias[ct] = fb[ct * 16 + l15];

#pragma unroll
    for (int r = 0; r < 4; r++) {
        int row = s0 + wave * 16 + l4 * 4 + r;
        size_t ro = ((size_t)b * S_ + row) * CC_;
        float z[16];
        float sum = 0.f;
#pragma unroll
        for (int ct = 0; ct < 16; ct++) {
            float zz = acc[ct][r] + fbias[ct] + bf2f(hb[ro + ct * 16 + l15]);
            z[ct] = zz;
            sum += zz;
        }
#pragma unroll
        for (int off = 1; off < 16; off <<= 1) sum += __shfl_xor(sum, off, 64);
        float mu = sum * (1.f / 256.f);
        float vs = 0.f;
#pragma unroll
        for (int ct = 0; ct < 16; ct++) {
            float d = z[ct] - mu;
            z[ct] = d;
            vs += d * d;
        }
#pragma unroll
        for (int off = 1; off < 16; off <<= 1) vs += __shfl_xor(vs, off, 64);
        float inv = rsqrtf(vs * (1.f / 256.f) + 1e-5f);
#pragma unroll
        for (int ct = 0; ct < 16; ct++) {
            int col = ct * 16 + l15;
            out[ro + col] = z[ct] * inv * g[col] + bbias[col];
        }
    }
}

// ---------------------------------------------------------------------------
extern "C" void kernel_launch(void* const* d_in, const int* in_sizes, int n_in,
                              void* d_out, int out_size, void* d_ws, size_t ws_size,
                              hipStream_t stream)
{
    const float* x      = (const float*)d_in[0];
    const void*  mask   = d_in[1];
    const float* conv_w = (const float*)d_in[2];
    const float* conv_b = (const float*)d_in[3];
    const float* wq     = (const float*)d_in[4];
    const float* bq     = (const float*)d_in[5];
    const float* wk     = (const float*)d_in[6];
    const float* bk     = (const float*)d_in[7];
    const float* wv     = (const float*)d_in[8];
    const float* bv     = (const float*)d_in[9];
    const float* fc_w   = (const float*)d_in[10];
    const float* fc_b   = (const float*)d_in[11];
    const float* ln_g   = (const float*)d_in[12];
    const float* ln_b   = (const float*)d_in[13];
    const float* gamma  = (const float*)d_in[14];
    const float* stdp   = (const float*)d_in[15];

    char* ws = (char*)d_ws;
    const size_t MB = 1024 * 1024;
    unsigned short* hb    = (unsigned short*)(ws);
    unsigned short* qb    = (unsigned short*)(ws + 8 * MB);
    unsigned short* kb    = (unsigned short*)(ws + 16 * MB);
    unsigned short* vb    = (unsigned short*)(ws + 24 * MB);
    unsigned short* ctxb  = (unsigned short*)(ws + 32 * MB);
    float*          ctab  = (float*)(ws + 40 * MB);           // 128 KB
    int*            lenv  = (int*)(ws + 40 * MB + 256 * 1024);
    unsigned short* wre2  = (unsigned short*)(ws + 41 * MB);
    unsigned short* wqkv2 = (unsigned short*)(ws + 42 * MB);
    unsigned short* wf2   = (unsigned short*)(ws + 43 * MB);

    prep_kernel<<<1928, 256, 0, stream>>>(conv_w, wq, wk, wv, fc_w, mask,
                                          gamma, stdp, wre2, wqkv2, wf2,
                                          ctab, lenv);
    dim3 g2(S_ / 64, B_);
    front_kernel<<<g2, 256, 0, stream>>>(x, wre2, conv_b, wqkv2, bq, bk, bv,
                                         hb, qb, kb, vb);
    dim3 ag(S_ / 128, NH_, B_);
    attn_mfma_kernel<<<ag, 256, 0, stream>>>(qb, kb, vb, ctab, lenv, ctxb);
    fc_ln_mfma_kernel<<<g2, 256, 0, stream>>>(ctxb, hb, wf2, fc_b, ln_g, ln_b,
                                              (float*)d_out);
}

// Round 15
// 186.507 us; speedup vs baseline: 1.0223x; 1.0223x over previous
//
#include <hip/hip_runtime.h>
#include <hip/hip_bf16.h>

#define B_ 8
#define S_ 2048
#define E_ 128
#define CC_ 256
#define H_ 256
#define NH_ 8
#define HD_ 32
#define KW_ 7

typedef __attribute__((ext_vector_type(8))) short bf16x8;
typedef __attribute__((ext_vector_type(4))) float f32x4;
typedef __attribute__((ext_vector_type(16))) float f32x16;

// fold 1/sqrt(HD) * log2(e) into Q so attention works in exp2 domain
#define QSCALE_ (0.17677669529663687f * 1.4426950408889634f)
#define CPEN_   0.7213475204444817f   /* 0.5 * log2(e) */

static __device__ __forceinline__ unsigned short f2bf(float f) {
    __hip_bfloat16 h = __float2bfloat16(f);
    return *(unsigned short*)&h;
}
static __device__ __forceinline__ float bf2f(unsigned short u) {
    __hip_bfloat16 h = *(__hip_bfloat16*)&u;
    return __bfloat162float(h);
}
// v_permlane32_swap: newA = [A.lo | B.lo], newB = [A.hi | B.hi]
static __device__ __forceinline__ void perm32swap(unsigned& a, unsigned& b) {
    asm volatile("s_nop 1\n\tv_permlane32_swap_b32 %0, %1" : "+v"(a), "+v"(b));
}

// ---------------------------------------------------------------------------
// Merged prep: weight reorders + packed (penalty,mask) table + lenv.
// ---------------------------------------------------------------------------
__global__ __launch_bounds__(256) void prep_kernel(
    const float* __restrict__ cw, const float* __restrict__ wq,
    const float* __restrict__ wk, const float* __restrict__ wv,
    const float* __restrict__ fw, const void* __restrict__ mask,
    const float* __restrict__ gamma_p, const float* __restrict__ std_p,
    unsigned short* __restrict__ wre2, unsigned short* __restrict__ wqkv2,
    unsigned short* __restrict__ wf2, unsigned* __restrict__ ctp,
    int* __restrict__ lenv)
{
    __shared__ int cnt[256];
    const int blk = blockIdx.x, tid = threadIdx.x;

    if (blk < 896) {                       // conv weights
        int i = blk * 256 + tid;
        int kl = i & 31, cc = (i >> 5) & 255, eb = (i >> 13) & 3, kk = i >> 15;
        wre2[i] = f2bf(cw[cc * (E_ * KW_) + (eb * 32 + kl) * KW_ + kk]);
    } else if (blk < 1664) {               // qkv weights
        int i = (blk - 896) * 256 + tid;
        int kl = i & 31, col = (i >> 5) & 255, kb = (i >> 13) & 7, m = i >> 16;
        const float* W = (m == 0) ? wq : (m == 1) ? wk : wv;
        wqkv2[i] = f2bf(W[(kb * 32 + kl) * H_ + col]);
    } else if (blk < 1920) {               // fc weights
        int i = (blk - 1664) * 256 + tid;
        int kl = i & 31, col = (i >> 5) & 255, kb = i >> 13;
        wf2[i] = f2bf(fw[(kb * 32 + kl) * CC_ + col]);
    } else {                               // penalty -> packed ctp + lenv
        int b = blk - 1920;

        uint32_t w0 = ((const uint32_t*)mask)[0];
        int mode = 0;
        if (w0 == 0x01010101u) mode = 1;
        else if (w0 == 0x3F803F80u) mode = 2;
        else if (w0 == 0x3F800000u) mode = 3;

        int c = 0;
        for (int s = tid; s < S_; s += 256) {
            bool vv;
            size_t i = (size_t)b * S_ + s;
            if (mode == 0)      vv = ((const int*)mask)[i] != 0;
            else if (mode == 1) vv = ((const unsigned char*)mask)[i] != 0;
            else if (mode == 2) vv = (((const unsigned short*)mask)[i] & 0x7FFFu) != 0;
            else                vv = ((const float*)mask)[i] != 0.f;
            c += vv ? 1 : 0;
        }
        cnt[tid] = c;
        __syncthreads();
        for (int off = 128; off > 0; off >>= 1) {
            if (tid < off) cnt[tid] += cnt[tid + off];
            __syncthreads();
        }
        int L = cnt[0];
        if (tid == 0) lenv[b] = L;

        float Lf = (float)L;
        float gamma = gamma_p[0];
        float sd = std_p[0];
        sd = fminf(fmaxf(sd, 0.01f), 0.5f);
        float scale = expf(gamma) - 1.f;
        float inv2s2 = 1.f / (2.f * sd * sd);
        unsigned* row = ctp + (size_t)b * S_;
        for (int s = tid; s < S_; s += 256) {
            float np = (s + 1.f) / (Lf + 1.f);
            float e = np - 0.5f;
            float base = expf(-(e * e) * inv2s2);
            bool vkk = s < L;
            unsigned short pen_h = vkk ? f2bf(-CPEN_ * base * scale) : (unsigned short)0;
            unsigned short msk_h = vkk ? (unsigned short)0 : f2bf(-1e10f);
            row[s] = (unsigned)pen_h | ((unsigned)msk_h << 16);
        }
    }
}

// ---------------------------------------------------------------------------
// Fused conv1d + QKV (unchanged)
// ---------------------------------------------------------------------------
__global__ __launch_bounds__(256) void front_kernel(
    const float* __restrict__ x, const unsigned short* __restrict__ wre2,
    const float* __restrict__ cb, const unsigned short* __restrict__ wqkv2,
    const float* __restrict__ bq, const float* __restrict__ bk,
    const float* __restrict__ bv, unsigned short* __restrict__ hb,
    unsigned short* __restrict__ qo, unsigned short* __restrict__ ko,
    unsigned short* __restrict__ vo)
{
    __shared__ __align__(16) char smem[64 * 264 * 2];   // 33792 B
    short (*xl)[136] = (short(*)[136])smem;             // 70x136 (19040 B)
    short (*Al)[264] = (short(*)[264])smem;             // 64x264 overlay

    const int tid = threadIdx.x, wave = tid >> 6, lane = tid & 63;
    const int l15 = lane & 15, l4 = lane >> 4;
    const int s0 = blockIdx.x * 64, b = blockIdx.y;

    // ---- stage x (f32 -> bf16) ----
    for (int idx = tid; idx < 70 * 32; idx += 256) {
        int row = idx >> 5, c4 = idx & 31;
        int pos = s0 - 3 + row;
        float4 v = {0.f, 0.f, 0.f, 0.f};
        if (pos >= 0 && pos < S_)
            v = *(const float4*)(x + ((size_t)b * S_ + pos) * E_ + c4 * 4);
        short* p = &xl[row][c4 * 4];
        p[0] = (short)f2bf(v.x); p[1] = (short)f2bf(v.y);
        p[2] = (short)f2bf(v.z); p[3] = (short)f2bf(v.w);
    }
    __syncthreads();

    // ---- conv: 7 shifted GEMMs ----
    f32x4 acc[4][4];
#pragma unroll
    for (int i = 0; i < 4; i++)
#pragma unroll
        for (int j = 0; j < 4; j++) acc[i][j] = (f32x4){0.f, 0.f, 0.f, 0.f};

#pragma unroll 1
    for (int kk = 0; kk < KW_; kk++) {
#pragma unroll
        for (int eb = 0; eb < 4; eb++) {
            const unsigned short* wp =
                wre2 + (((size_t)(kk * 4 + eb) * 256 + wave * 64 + l15) * 32) + l4 * 8;
            bf16x8 af[4], bfr[4];
#pragma unroll
            for (int ct = 0; ct < 4; ct++)
                bfr[ct] = *(const bf16x8*)(wp + ct * 512);
#pragma unroll
            for (int rt = 0; rt < 4; rt++)
                af[rt] = *(const bf16x8*)(&xl[rt * 16 + l15 + kk][eb * 32 + l4 * 8]);
#pragma unroll
            for (int rt = 0; rt < 4; rt++)
#pragma unroll
                for (int ct = 0; ct < 4; ct++)
                    acc[rt][ct] = __builtin_amdgcn_mfma_f32_16x16x32_bf16(
                        af[rt], bfr[ct], acc[rt][ct], 0, 0, 0);
        }
    }
    __syncthreads();   // all waves done reading xl -> safe to overlay Al

    // ---- epilogue: bias + relu -> Al (bf16) ----
#pragma unroll
    for (int ct = 0; ct < 4; ct++) {
        int col = wave * 64 + ct * 16 + l15;
        float bias = cb[col];
#pragma unroll
        for (int rt = 0; rt < 4; rt++)
#pragma unroll
            for (int r = 0; r < 4; r++) {
                float v0 = acc[rt][ct][r] + bias;
                v0 = v0 > 0.f ? v0 : 0.f;
                Al[rt * 16 + l4 * 4 + r][col] = (short)f2bf(v0);
            }
    }
    __syncthreads();

    // ---- copy h tile to global (coalesced) ----
    for (int idx = tid; idx < 64 * 32; idx += 256) {
        int row = idx >> 5, c8 = idx & 31;
        *(bf16x8*)(hb + ((size_t)b * S_ + s0 + row) * CC_ + c8 * 8) =
            *(const bf16x8*)(&Al[row][c8 * 8]);
    }

    // ---- QKV GEMMs from Al ----
#pragma unroll 1
    for (int m = 0; m < 3; m++) {
        f32x4 qacc[4][4];
#pragma unroll
        for (int i = 0; i < 4; i++)
#pragma unroll
            for (int j = 0; j < 4; j++) qacc[i][j] = (f32x4){0.f, 0.f, 0.f, 0.f};

#pragma unroll 1
        for (int kb8 = 0; kb8 < 8; kb8++) {
            const unsigned short* wp =
                wqkv2 + (((size_t)(m * 8 + kb8) * 256 + wave * 64 + l15) * 32) + l4 * 8;
            bf16x8 af[4], bfr[4];
#pragma unroll
            for (int ct = 0; ct < 4; ct++)
                bfr[ct] = *(const bf16x8*)(wp + ct * 512);
#pragma unroll
            for (int rt = 0; rt < 4; rt++)
                af[rt] = *(const bf16x8*)(&Al[rt * 16 + l15][kb8 * 32 + l4 * 8]);
#pragma unroll
            for (int rt = 0; rt < 4; rt++)
#pragma unroll
                for (int ct = 0; ct < 4; ct++)
                    qacc[rt][ct] = __builtin_amdgcn_mfma_f32_16x16x32_bf16(
                        af[rt], bfr[ct], qacc[rt][ct], 0, 0, 0);
        }

        const float* bias_p = (m == 0) ? bq : (m == 1) ? bk : bv;
        unsigned short* O = (m == 0) ? qo : (m == 1) ? ko : vo;
        const float oscale = (m == 0) ? QSCALE_ : 1.f;
#pragma unroll
        for (int ct = 0; ct < 4; ct++) {
            int col = wave * 64 + ct * 16 + l15;
            float bias = bias_p[col];
            int n = col >> 5, d = col & 31;
#pragma unroll
            for (int rt = 0; rt < 4; rt++)
#pragma unroll
                for (int r = 0; r < 4; r++) {
                    int row = s0 + rt * 16 + l4 * 4 + r;
                    O[(((size_t)b * NH_ + n) * S_ + row) * HD_ + d] =
                        f2bf((qacc[rt][ct][r] + bias) * oscale);
                }
        }
    }
}

// ---------------------------------------------------------------------------
// MFMA flash attention v12: penalty+mask folded into the QK^T inner product
// via 2 augmented k-dims living in Kt's pad bytes (dims 32,33); third MFMA
// per subtile with shared-zero C. No ctC buffer, no C-init reads/movs.
// KV tile 128 (R13 geometry), Σ-via-MFMA denominator, permlane P, setprio,
// double-buffered 1-barrier staging, round-7 grid.
// ---------------------------------------------------------------------------
__global__ __launch_bounds__(256) void attn_mfma_kernel(
    const unsigned short* __restrict__ q, const unsigned short* __restrict__ k,
    const unsigned short* __restrict__ v, const unsigned* __restrict__ ctp,
    const int* __restrict__ lenv, unsigned short* __restrict__ ctxb)
{
    __shared__ short Kt[2][128][40];   // dims 0..31 = K, 32 = pen, 33 = mask, 34..39 = 0
    __shared__ short Vt[2][32][136];   // [d][key], chunk-swizzled

    const int tid = threadIdx.x;
    const int wave = tid >> 6, lane = tid & 63;
    const int r31 = lane & 31, hi = lane >> 5;
    const int hi8 = hi * 8, hi4 = hi * 4;

    const int qt = blockIdx.x, n = blockIdx.y, b = blockIdx.z;
    const int qrow = qt * 128 + wave * 32 + r31;
    const int L = lenv[b];
    const int nt = (L + 127) >> 7;

    const size_t head = ((size_t)b * NH_ + n) * S_;
    const unsigned short* qbase = q + head * HD_;
    const unsigned short* kbase = k + head * HD_;
    const unsigned short* vbase = v + head * HD_;
    const unsigned* ctpb = ctp + (size_t)b * S_;

    bf16x8 qf0 = *(const bf16x8*)(qbase + (size_t)qrow * HD_ + hi8);
    bf16x8 qf1 = *(const bf16x8*)(qbase + (size_t)qrow * HD_ + 16 + hi8);

    // extended Q fragment: dim32 = vq (gates penalty), dim33 = 1.0 (gates mask)
    bf16x8 qe;
#pragma unroll
    for (int i = 0; i < 8; i++) qe[i] = 0;
    if (hi == 0) {
        qe[0] = (qrow < L) ? (short)0x3F80 : (short)0;
        qe[1] = (short)0x3F80;
    }

    // constant 1.0-bf16 A-fragment for the sum-MFMA; shared zero C operand
    bf16x8 ones;
#pragma unroll
    for (int i = 0; i < 8; i++) ones[i] = (short)0x3F80;
    f32x16 zc;
#pragma unroll
    for (int r = 0; r < 16; r++) zc[r] = 0.f;

    f32x16 acc, acc_l;
#pragma unroll
    for (int r = 0; r < 16; r++) { acc[r] = 0.f; acc_l[r] = 0.f; }
    float m_r = 0.f;

    // staging: 256 threads, 2 bf16x8 per thread (keys x d halves)
    const int krow = tid >> 1, kch = (tid & 1) * 16;
    const int d7x2 = 2 * (r31 & 7);
    const int vc = krow >> 3, vk7 = krow & 7;

    bf16x8 kreg0, kreg1, va, vb;
    unsigned cw = 0;

    // ---- prologue ----
    kreg0 = *(const bf16x8*)(kbase + (size_t)krow * HD_ + kch);
    kreg1 = *(const bf16x8*)(kbase + (size_t)krow * HD_ + kch + 8);
    va    = *(const bf16x8*)(vbase + (size_t)krow * HD_ + kch);
    vb    = *(const bf16x8*)(vbase + (size_t)krow * HD_ + kch + 8);
    if (tid < 128) cw = ctpb[tid];
    {
        // zero the pad dims 34..39 of every row (both buffers) once — kf2
        // reads them multiplied by Q=0; uninit NaN would poison the MFMA.
        short* pr = &Kt[tid >> 7][tid & 127][34];
        *(unsigned*)(pr) = 0; *(unsigned*)(pr + 2) = 0; *(unsigned*)(pr + 4) = 0;
        // row127/buf0's kf2-hi1 overruns into Kt[1][0][0..8): zero before tile0
        if (tid < 4) *(unsigned*)(&Kt[1][0][tid * 2]) = 0;

        *(bf16x8*)(&Kt[0][krow][kch])     = kreg0;
        *(bf16x8*)(&Kt[0][krow][kch + 8]) = kreg1;
#pragma unroll
        for (int i = 0; i < 8; i++) {
            int d0 = kch + i, d1 = kch + 8 + i;
            Vt[0][d0][((((vc - 2 * (d0 & 7)) & 7) | (vc & 8)) << 3) + vk7] = va[i];
            Vt[0][d1][((((vc - 2 * (d1 & 7)) & 7) | (vc & 8)) << 3) + vk7] = vb[i];
        }
        if (tid < 128) *(unsigned*)(&Kt[0][tid][32]) = cw;
    }
    __syncthreads();

#pragma unroll 1
    for (int t = 0; t < nt; t++) {
        const int cur = t & 1;
        const int knext = (t + 1) << 7;
        const bool more = (t + 1 < nt);

        // ---- ISSUE next tile's global loads ----
        if (more) {
            kreg0 = *(const bf16x8*)(kbase + (size_t)(knext + krow) * HD_ + kch);
            kreg1 = *(const bf16x8*)(kbase + (size_t)(knext + krow) * HD_ + kch + 8);
            va    = *(const bf16x8*)(vbase + (size_t)(knext + krow) * HD_ + kch);
            vb    = *(const bf16x8*)(vbase + (size_t)(knext + krow) * HD_ + kch + 8);
            if (tid < 128) cw = ctpb[knext + tid];
        }

        // ---- QK^T: 3 MFMAs/subtile; penalty+mask ride dims 32,33 ----
        __builtin_amdgcn_s_setprio(1);
        f32x16 sc[4];
#pragma unroll
        for (int t4 = 0; t4 < 4; t4++) {
            const short* kr = &Kt[cur][t4 * 32 + r31][0];
            bf16x8 kf0 = *(const bf16x8*)(kr + hi8);
            bf16x8 kf1 = *(const bf16x8*)(kr + 16 + hi8);
            bf16x8 kf2 = *(const bf16x8*)(kr + 32 + hi8);
            f32x16 s0 = __builtin_amdgcn_mfma_f32_32x32x16_bf16(kf0, qf0, zc, 0, 0, 0);
            f32x16 s1 = __builtin_amdgcn_mfma_f32_32x32x16_bf16(kf1, qf1, s0, 0, 0, 0);
            sc[t4]    = __builtin_amdgcn_mfma_f32_32x32x16_bf16(kf2, qe,  s1, 0, 0, 0);
        }
        __builtin_amdgcn_s_setprio(0);

        // ---- row max: 4 parallel chains, max3-fusable; lane-local ----
        float mxa[4];
#pragma unroll
        for (int g = 0; g < 4; g++) mxa[g] = -1e30f;
#pragma unroll
        for (int t4 = 0; t4 < 4; t4++)
#pragma unroll
            for (int g = 0; g < 4; g++)
                mxa[g] = fmaxf(fmaxf(fmaxf(mxa[g], sc[t4][g * 4]),
                                     fmaxf(sc[t4][g * 4 + 1], sc[t4][g * 4 + 2])),
                               sc[t4][g * 4 + 3]);
        float pmx = fmaxf(fmaxf(mxa[0], mxa[1]), fmaxf(mxa[2], mxa[3]));

        // ---- defer-max: rare rescale (shfl only inside) ----
        if (!__all(pmx <= m_r + 8.f)) {
            pmx = fmaxf(pmx, __shfl_xor(pmx, 32, 64));
            float mn = fmaxf(m_r, pmx);
            float alpha = exp2f(m_r - mn);
            m_r = mn;
#pragma unroll
            for (int r = 0; r < 16; r++) acc[r] *= alpha;
            acc_l[0] *= alpha;
        }
        // scores are raw; subtract the running max only once it's nonzero
        if (__any(m_r != 0.f)) {
#pragma unroll
            for (int t4 = 0; t4 < 4; t4++)
#pragma unroll
                for (int r = 0; r < 16; r++) sc[t4][r] -= m_r;
        }

        // ---- p = exp2(s), pack to bf16 + permlane ----
        unsigned pk[4][8];
#pragma unroll
        for (int t4 = 0; t4 < 4; t4++) {
            unsigned U[8];
#pragma unroll
            for (int j = 0; j < 8; j++) {
                float pa = exp2f(sc[t4][2 * j]);
                float pb = exp2f(sc[t4][2 * j + 1]);
                U[j] = (unsigned)f2bf(pa) | ((unsigned)f2bf(pb) << 16);
            }
            perm32swap(U[0], U[2]);
            perm32swap(U[1], U[3]);
            perm32swap(U[4], U[6]);
            perm32swap(U[5], U[7]);
            pk[t4][0] = U[0]; pk[t4][1] = U[1]; pk[t4][2] = U[2]; pk[t4][3] = U[3];
            pk[t4][4] = U[4]; pk[t4][5] = U[5]; pk[t4][6] = U[6]; pk[t4][7] = U[7];
        }

        // ---- PV + sum-MFMA ----
        __builtin_amdgcn_s_setprio(1);
#pragma unroll
        for (int t4 = 0; t4 < 4; t4++) {
            union { unsigned u[4]; bf16x8 v8; } pb0, pb1;
            pb0.u[0] = pk[t4][0]; pb0.u[1] = pk[t4][1];
            pb0.u[2] = pk[t4][2]; pb0.u[3] = pk[t4][3];
            pb1.u[0] = pk[t4][4]; pb1.u[1] = pk[t4][5];
            pb1.u[2] = pk[t4][6]; pb1.u[3] = pk[t4][7];
            int c0i = t4 * 4 + hi, c1i = t4 * 4 + 2 + hi;
            bf16x8 vf0 = *(const bf16x8*)(&Vt[cur][r31][(((c0i - d7x2) & 7) | (c0i & 8)) << 3]);
            bf16x8 vf1 = *(const bf16x8*)(&Vt[cur][r31][(((c1i - d7x2) & 7) | (c1i & 8)) << 3]);
            acc   = __builtin_amdgcn_mfma_f32_32x32x16_bf16(vf0, pb0.v8, acc, 0, 0, 0);
            acc_l = __builtin_amdgcn_mfma_f32_32x32x16_bf16(ones, pb0.v8, acc_l, 0, 0, 0);
            acc   = __builtin_amdgcn_mfma_f32_32x32x16_bf16(vf1, pb1.v8, acc, 0, 0, 0);
            acc_l = __builtin_amdgcn_mfma_f32_32x32x16_bf16(ones, pb1.v8, acc_l, 0, 0, 0);
        }
        __builtin_amdgcn_s_setprio(0);

        // ---- WRITE next tile, single barrier ----
        if (more) {
            const int nxt = cur ^ 1;
            *(bf16x8*)(&Kt[nxt][krow][kch])     = kreg0;
            *(bf16x8*)(&Kt[nxt][krow][kch + 8]) = kreg1;
#pragma unroll
            for (int i = 0; i < 8; i++) {
                int d0 = kch + i, d1 = kch + 8 + i;
                Vt[nxt][d0][((((vc - 2 * (d0 & 7)) & 7) | (vc & 8)) << 3) + vk7] = va[i];
                Vt[nxt][d1][((((vc - 2 * (d1 & 7)) & 7) | (vc & 8)) << 3) + vk7] = vb[i];
            }
            if (tid < 128) *(unsigned*)(&Kt[nxt][tid][32]) = cw;
            __syncthreads();
        }
    }

    // epilogue: out[d][q] -> ctx row q; denominator from acc_l[0]
    float inv = 1.f / acc_l[0];
    size_t obase = ((size_t)b * S_ + qrow) * H_ + n * HD_;
#pragma unroll
    for (int g = 0; g < 4; g++)
#pragma unroll
        for (int w = 0; w < 2; w++) {
            unsigned uo = (unsigned)f2bf(acc[g * 4 + w * 2] * inv) |
                          ((unsigned)f2bf(acc[g * 4 + w * 2 + 1] * inv) << 16);
            int d = 8 * g + hi4 + 2 * w;
            *(unsigned*)(ctxb + obase + d) = uo;
        }
}

// ---------------------------------------------------------------------------
// FC GEMM + residual + LayerNorm fused (unchanged)
// ---------------------------------------------------------------------------
__global__ __launch_bounds__(256) void fc_ln_mfma_kernel(
    const unsigned short* __restrict__ ctxb, const unsigned short* __restrict__ hb,
    const unsigned short* __restrict__ wf2, const float* __restrict__ fb,
    const float* __restrict__ g, const float* __restrict__ bbias,
    float* __restrict__ out)
{
    const int tid = threadIdx.x, wave = tid >> 6, lane = tid & 63;
    const int l15 = lane & 15, l4 = lane >> 4;
    const int s0 = blockIdx.x * 64, b = blockIdx.y;
    const int arow = s0 + wave * 16 + l15;

    bf16x8 af[8];
#pragma unroll
    for (int kb = 0; kb < 8; kb++)
        af[kb] = *(const bf16x8*)(ctxb + (size_t)((size_t)b * S_ + arow) * H_ + kb * 32 + l4 * 8);

    f32x4 acc[16];
#pragma unroll
    for (int ct = 0; ct < 16; ct++) acc[ct] = (f32x4){0.f, 0.f, 0.f, 0.f};

#pragma unroll 1
    for (int kb = 0; kb < 8; kb++) {
        const unsigned short* wp = wf2 + ((size_t)kb * 256 + l15) * 32 + l4 * 8;
#pragma unroll
        for (int ct = 0; ct < 16; ct++) {
            bf16x8 bfr = *(const bf16x8*)(wp + ct * 512);
            acc[ct] = __builtin_amdgcn_mfma_f32_16x16x32_bf16(af[kb], bfr, acc[ct], 0, 0, 0);
        }
    }

    float fbias[16];
#pragma unroll
    for (int ct = 0; ct < 16; ct++) fbias[ct] = fb[ct * 16 + l15];

#pragma unroll
    for (int r = 0; r < 4; r++) {
        int row = s0 + wave * 16 + l4 * 4 + r;
        size_t ro = ((size_t)b * S_ + row) * CC_;
        float z[16];
        float sum = 0.f;
#pragma unroll
        for (int ct = 0; ct < 16; ct++) {
            float zz = acc[ct][r] + fbias[ct] + bf2f(hb[ro + ct * 16 + l15]);
            z[ct] = zz;
            sum += zz;
        }
#pragma unroll
        for (int off = 1; off < 16; off <<= 1) sum += __shfl_xor(sum, off, 64);
        float mu = sum * (1.f / 256.f);
        float vs = 0.f;
#pragma unroll
        for (int ct = 0; ct < 16; ct++) {
            float d = z[ct] - mu;
            z[ct] = d;
            vs += d * d;
        }
#pragma unroll
        for (int off = 1; off < 16; off <<= 1) vs += __shfl_xor(vs, off, 64);
        float inv = rsqrtf(vs * (1.f / 256.f) + 1e-5f);
#pragma unroll
        for (int ct = 0; ct < 16; ct++) {
            int col = ct * 16 + l15;
            out[ro + col] = z[ct] * inv * g[col] + bbias[col];
        }
    }
}

// ---------------------------------------------------------------------------
extern "C" void kernel_launch(void* const* d_in, const int* in_sizes, int n_in,
                              void* d_out, int out_size, void* d_ws, size_t ws_size,
                              hipStream_t stream)
{
    const float* x      = (const float*)d_in[0];
    const void*  mask   = d_in[1];
    const float* conv_w = (const float*)d_in[2];
    const float* conv_b = (const float*)d_in[3];
    const float* wq     = (const float*)d_in[4];
    const float* bq     = (const float*)d_in[5];
    const float* wk     = (const float*)d_in[6];
    const float* bk     = (const float*)d_in[7];
    const float* wv     = (const float*)d_in[8];
    const float* bv     = (const float*)d_in[9];
    const float* fc_w   = (const float*)d_in[10];
    const float* fc_b   = (const float*)d_in[11];
    const float* ln_g   = (const float*)d_in[12];
    const float* ln_b   = (const float*)d_in[13];
    const float* gamma  = (const float*)d_in[14];
    const float* stdp   = (const float*)d_in[15];

    char* ws = (char*)d_ws;
    const size_t MB = 1024 * 1024;
    unsigned short* hb    = (unsigned short*)(ws);
    unsigned short* qb    = (unsigned short*)(ws + 8 * MB);
    unsigned short* kb    = (unsigned short*)(ws + 16 * MB);
    unsigned short* vb    = (unsigned short*)(ws + 24 * MB);
    unsigned short* ctxb  = (unsigned short*)(ws + 32 * MB);
    unsigned*       ctp   = (unsigned*)(ws + 40 * MB);        // 64 KB packed
    int*            lenv  = (int*)(ws + 40 * MB + 256 * 1024);
    unsigned short* wre2  = (unsigned short*)(ws + 41 * MB);
    unsigned short* wqkv2 = (unsigned short*)(ws + 42 * MB);
    unsigned short* wf2   = (unsigned short*)(ws + 43 * MB);

    prep_kernel<<<1928, 256, 0, stream>>>(conv_w, wq, wk, wv, fc_w, mask,
                                          gamma, stdp, wre2, wqkv2, wf2,
                                          ctp, lenv);
    dim3 g2(S_ / 64, B_);
    front_kernel<<<g2, 256, 0, stream>>>(x, wre2, conv_b, wqkv2, bq, bk, bv,
                                         hb, qb, kb, vb);
    dim3 ag(S_ / 128, NH_, B_);
    attn_mfma_kernel<<<ag, 256, 0, stream>>>(qb, kb, vb, ctp, lenv, ctxb);
    fc_ln_mfma_kernel<<<g2, 256, 0, stream>>>(ctxb, hb, wf2, fc_b, ln_g, ln_b,
                                              (float*)d_out);
}

// Round 16
// 180.827 us; speedup vs baseline: 1.0544x; 1.0314x over previous
//
#include <hip/hip_runtime.h>
#include <hip/hip_bf16.h>

#define B_ 8
#define S_ 2048
#define E_ 128
#define CC_ 256
#define H_ 256
#define NH_ 8
#define HD_ 32
#define KW_ 7

typedef __attribute__((ext_vector_type(8))) short bf16x8;
typedef __attribute__((ext_vector_type(4))) float f32x4;
typedef __attribute__((ext_vector_type(16))) float f32x16;

// fold 1/sqrt(HD) * log2(e) into Q so attention works in exp2 domain
#define QSCALE_ (0.17677669529663687f * 1.4426950408889634f)
#define CPEN_   0.7213475204444817f   /* 0.5 * log2(e) */

static __device__ __forceinline__ unsigned short f2bf(float f) {
    __hip_bfloat16 h = __float2bfloat16(f);
    return *(unsigned short*)&h;
}
static __device__ __forceinline__ float bf2f(unsigned short u) {
    __hip_bfloat16 h = *(__hip_bfloat16*)&u;
    return __bfloat162float(h);
}
// one-instruction packed f32x2 -> bf16x2 (RNE), T12 recipe (no builtin)
static __device__ __forceinline__ unsigned cvtpk(float lo, float hi) {
    unsigned r;
    asm("v_cvt_pk_bf16_f32 %0, %1, %2" : "=v"(r) : "v"(lo), "v"(hi));
    return r;
}
// v_permlane32_swap: newA = [A.lo | B.lo], newB = [A.hi | B.hi]
static __device__ __forceinline__ void perm32swap(unsigned& a, unsigned& b) {
    asm volatile("s_nop 1\n\tv_permlane32_swap_b32 %0, %1" : "+v"(a), "+v"(b));
}

// ---------------------------------------------------------------------------
// Merged prep: weight reorders + packed (penalty,mask) table + lenv.
// ---------------------------------------------------------------------------
__global__ __launch_bounds__(256) void prep_kernel(
    const float* __restrict__ cw, const float* __restrict__ wq,
    const float* __restrict__ wk, const float* __restrict__ wv,
    const float* __restrict__ fw, const void* __restrict__ mask,
    const float* __restrict__ gamma_p, const float* __restrict__ std_p,
    unsigned short* __restrict__ wre2, unsigned short* __restrict__ wqkv2,
    unsigned short* __restrict__ wf2, unsigned* __restrict__ ctp,
    int* __restrict__ lenv)
{
    __shared__ int cnt[256];
    const int blk = blockIdx.x, tid = threadIdx.x;

    if (blk < 896) {                       // conv weights
        int i = blk * 256 + tid;
        int kl = i & 31, cc = (i >> 5) & 255, eb = (i >> 13) & 3, kk = i >> 15;
        wre2[i] = f2bf(cw[cc * (E_ * KW_) + (eb * 32 + kl) * KW_ + kk]);
    } else if (blk < 1664) {               // qkv weights
        int i = (blk - 896) * 256 + tid;
        int kl = i & 31, col = (i >> 5) & 255, kb = (i >> 13) & 7, m = i >> 16;
        const float* W = (m == 0) ? wq : (m == 1) ? wk : wv;
        wqkv2[i] = f2bf(W[(kb * 32 + kl) * H_ + col]);
    } else if (blk < 1920) {               // fc weights
        int i = (blk - 1664) * 256 + tid;
        int kl = i & 31, col = (i >> 5) & 255, kb = i >> 13;
        wf2[i] = f2bf(fw[(kb * 32 + kl) * CC_ + col]);
    } else {                               // penalty -> packed ctp + lenv
        int b = blk - 1920;

        uint32_t w0 = ((const uint32_t*)mask)[0];
        int mode = 0;
        if (w0 == 0x01010101u) mode = 1;
        else if (w0 == 0x3F803F80u) mode = 2;
        else if (w0 == 0x3F800000u) mode = 3;

        int c = 0;
        for (int s = tid; s < S_; s += 256) {
            bool vv;
            size_t i = (size_t)b * S_ + s;
            if (mode == 0)      vv = ((const int*)mask)[i] != 0;
            else if (mode == 1) vv = ((const unsigned char*)mask)[i] != 0;
            else if (mode == 2) vv = (((const unsigned short*)mask)[i] & 0x7FFFu) != 0;
            else                vv = ((const float*)mask)[i] != 0.f;
            c += vv ? 1 : 0;
        }
        cnt[tid] = c;
        __syncthreads();
        for (int off = 128; off > 0; off >>= 1) {
            if (tid < off) cnt[tid] += cnt[tid + off];
            __syncthreads();
        }
        int L = cnt[0];
        if (tid == 0) lenv[b] = L;

        float Lf = (float)L;
        float gamma = gamma_p[0];
        float sd = std_p[0];
        sd = fminf(fmaxf(sd, 0.01f), 0.5f);
        float scale = expf(gamma) - 1.f;
        float inv2s2 = 1.f / (2.f * sd * sd);
        unsigned* row = ctp + (size_t)b * S_;
        for (int s = tid; s < S_; s += 256) {
            float np = (s + 1.f) / (Lf + 1.f);
            float e = np - 0.5f;
            float base = expf(-(e * e) * inv2s2);
            bool vkk = s < L;
            unsigned short pen_h = vkk ? f2bf(-CPEN_ * base * scale) : (unsigned short)0;
            unsigned short msk_h = vkk ? (unsigned short)0 : f2bf(-1e10f);
            row[s] = (unsigned)pen_h | ((unsigned)msk_h << 16);
        }
    }
}

// ---------------------------------------------------------------------------
// Fused conv1d + QKV (unchanged)
// ---------------------------------------------------------------------------
__global__ __launch_bounds__(256) void front_kernel(
    const float* __restrict__ x, const unsigned short* __restrict__ wre2,
    const float* __restrict__ cb, const unsigned short* __restrict__ wqkv2,
    const float* __restrict__ bq, const float* __restrict__ bk,
    const float* __restrict__ bv, unsigned short* __restrict__ hb,
    unsigned short* __restrict__ qo, unsigned short* __restrict__ ko,
    unsigned short* __restrict__ vo)
{
    __shared__ __align__(16) char smem[64 * 264 * 2];   // 33792 B
    short (*xl)[136] = (short(*)[136])smem;             // 70x136 (19040 B)
    short (*Al)[264] = (short(*)[264])smem;             // 64x264 overlay

    const int tid = threadIdx.x, wave = tid >> 6, lane = tid & 63;
    const int l15 = lane & 15, l4 = lane >> 4;
    const int s0 = blockIdx.x * 64, b = blockIdx.y;

    // ---- stage x (f32 -> bf16) ----
    for (int idx = tid; idx < 70 * 32; idx += 256) {
        int row = idx >> 5, c4 = idx & 31;
        int pos = s0 - 3 + row;
        float4 v = {0.f, 0.f, 0.f, 0.f};
        if (pos >= 0 && pos < S_)
            v = *(const float4*)(x + ((size_t)b * S_ + pos) * E_ + c4 * 4);
        short* p = &xl[row][c4 * 4];
        p[0] = (short)f2bf(v.x); p[1] = (short)f2bf(v.y);
        p[2] = (short)f2bf(v.z); p[3] = (short)f2bf(v.w);
    }
    __syncthreads();

    // ---- conv: 7 shifted GEMMs ----
    f32x4 acc[4][4];
#pragma unroll
    for (int i = 0; i < 4; i++)
#pragma unroll
        for (int j = 0; j < 4; j++) acc[i][j] = (f32x4){0.f, 0.f, 0.f, 0.f};

#pragma unroll 1
    for (int kk = 0; kk < KW_; kk++) {
#pragma unroll
        for (int eb = 0; eb < 4; eb++) {
            const unsigned short* wp =
                wre2 + (((size_t)(kk * 4 + eb) * 256 + wave * 64 + l15) * 32) + l4 * 8;
            bf16x8 af[4], bfr[4];
#pragma unroll
            for (int ct = 0; ct < 4; ct++)
                bfr[ct] = *(const bf16x8*)(wp + ct * 512);
#pragma unroll
            for (int rt = 0; rt < 4; rt++)
                af[rt] = *(const bf16x8*)(&xl[rt * 16 + l15 + kk][eb * 32 + l4 * 8]);
#pragma unroll
            for (int rt = 0; rt < 4; rt++)
#pragma unroll
                for (int ct = 0; ct < 4; ct++)
                    acc[rt][ct] = __builtin_amdgcn_mfma_f32_16x16x32_bf16(
                        af[rt], bfr[ct], acc[rt][ct], 0, 0, 0);
        }
    }
    __syncthreads();   // all waves done reading xl -> safe to overlay Al

    // ---- epilogue: bias + relu -> Al (bf16) ----
#pragma unroll
    for (int ct = 0; ct < 4; ct++) {
        int col = wave * 64 + ct * 16 + l15;
        float bias = cb[col];
#pragma unroll
        for (int rt = 0; rt < 4; rt++)
#pragma unroll
            for (int r = 0; r < 4; r++) {
                float v0 = acc[rt][ct][r] + bias;
                v0 = v0 > 0.f ? v0 : 0.f;
                Al[rt * 16 + l4 * 4 + r][col] = (short)f2bf(v0);
            }
    }
    __syncthreads();

    // ---- copy h tile to global (coalesced) ----
    for (int idx = tid; idx < 64 * 32; idx += 256) {
        int row = idx >> 5, c8 = idx & 31;
        *(bf16x8*)(hb + ((size_t)b * S_ + s0 + row) * CC_ + c8 * 8) =
            *(const bf16x8*)(&Al[row][c8 * 8]);
    }

    // ---- QKV GEMMs from Al ----
#pragma unroll 1
    for (int m = 0; m < 3; m++) {
        f32x4 qacc[4][4];
#pragma unroll
        for (int i = 0; i < 4; i++)
#pragma unroll
            for (int j = 0; j < 4; j++) qacc[i][j] = (f32x4){0.f, 0.f, 0.f, 0.f};

#pragma unroll 1
        for (int kb8 = 0; kb8 < 8; kb8++) {
            const unsigned short* wp =
                wqkv2 + (((size_t)(m * 8 + kb8) * 256 + wave * 64 + l15) * 32) + l4 * 8;
            bf16x8 af[4], bfr[4];
#pragma unroll
            for (int ct = 0; ct < 4; ct++)
                bfr[ct] = *(const bf16x8*)(wp + ct * 512);
#pragma unroll
            for (int rt = 0; rt < 4; rt++)
                af[rt] = *(const bf16x8*)(&Al[rt * 16 + l15][kb8 * 32 + l4 * 8]);
#pragma unroll
            for (int rt = 0; rt < 4; rt++)
#pragma unroll
                for (int ct = 0; ct < 4; ct++)
                    qacc[rt][ct] = __builtin_amdgcn_mfma_f32_16x16x32_bf16(
                        af[rt], bfr[ct], qacc[rt][ct], 0, 0, 0);
        }

        const float* bias_p = (m == 0) ? bq : (m == 1) ? bk : bv;
        unsigned short* O = (m == 0) ? qo : (m == 1) ? ko : vo;
        const float oscale = (m == 0) ? QSCALE_ : 1.f;
#pragma unroll
        for (int ct = 0; ct < 4; ct++) {
            int col = wave * 64 + ct * 16 + l15;
            float bias = bias_p[col];
            int n = col >> 5, d = col & 31;
#pragma unroll
            for (int rt = 0; rt < 4; rt++)
#pragma unroll
                for (int r = 0; r < 4; r++) {
                    int row = s0 + rt * 16 + l4 * 4 + r;
                    O[(((size_t)b * NH_ + n) * S_ + row) * HD_ + d] =
                        f2bf((qacc[rt][ct][r] + bias) * oscale);
                }
        }
    }
}

// ---------------------------------------------------------------------------
// MFMA flash attention v13 = v12 + v_cvt_pk_bf16_f32 P-pack (one instr per
// score pair instead of scalar RNE casts + or/shift). All else unchanged:
// penalty+mask as augmented k-dims, Σ-via-MFMA denominator, permlane P,
// defer-max, setprio, double-buffered 1-barrier staging, round-7 grid.
// ---------------------------------------------------------------------------
__global__ __launch_bounds__(256) void attn_mfma_kernel(
    const unsigned short* __restrict__ q, const unsigned short* __restrict__ k,
    const unsigned short* __restrict__ v, const unsigned* __restrict__ ctp,
    const int* __restrict__ lenv, unsigned short* __restrict__ ctxb)
{
    __shared__ short Kt[2][128][40];   // dims 0..31 = K, 32 = pen, 33 = mask, 34..39 = 0
    __shared__ short Vt[2][32][136];   // [d][key], chunk-swizzled

    const int tid = threadIdx.x;
    const int wave = tid >> 6, lane = tid & 63;
    const int r31 = lane & 31, hi = lane >> 5;
    const int hi8 = hi * 8, hi4 = hi * 4;

    const int qt = blockIdx.x, n = blockIdx.y, b = blockIdx.z;
    const int qrow = qt * 128 + wave * 32 + r31;
    const int L = lenv[b];
    const int nt = (L + 127) >> 7;

    const size_t head = ((size_t)b * NH_ + n) * S_;
    const unsigned short* qbase = q + head * HD_;
    const unsigned short* kbase = k + head * HD_;
    const unsigned short* vbase = v + head * HD_;
    const unsigned* ctpb = ctp + (size_t)b * S_;

    bf16x8 qf0 = *(const bf16x8*)(qbase + (size_t)qrow * HD_ + hi8);
    bf16x8 qf1 = *(const bf16x8*)(qbase + (size_t)qrow * HD_ + 16 + hi8);

    // extended Q fragment: dim32 = vq (gates penalty), dim33 = 1.0 (gates mask)
    bf16x8 qe;
#pragma unroll
    for (int i = 0; i < 8; i++) qe[i] = 0;
    if (hi == 0) {
        qe[0] = (qrow < L) ? (short)0x3F80 : (short)0;
        qe[1] = (short)0x3F80;
    }

    // constant 1.0-bf16 A-fragment for the sum-MFMA; shared zero C operand
    bf16x8 ones;
#pragma unroll
    for (int i = 0; i < 8; i++) ones[i] = (short)0x3F80;
    f32x16 zc;
#pragma unroll
    for (int r = 0; r < 16; r++) zc[r] = 0.f;

    f32x16 acc, acc_l;
#pragma unroll
    for (int r = 0; r < 16; r++) { acc[r] = 0.f; acc_l[r] = 0.f; }
    float m_r = 0.f;

    // staging: 256 threads, 2 bf16x8 per thread (keys x d halves)
    const int krow = tid >> 1, kch = (tid & 1) * 16;
    const int d7x2 = 2 * (r31 & 7);
    const int vc = krow >> 3, vk7 = krow & 7;

    bf16x8 kreg0, kreg1, va, vb;
    unsigned cw = 0;

    // ---- prologue ----
    kreg0 = *(const bf16x8*)(kbase + (size_t)krow * HD_ + kch);
    kreg1 = *(const bf16x8*)(kbase + (size_t)krow * HD_ + kch + 8);
    va    = *(const bf16x8*)(vbase + (size_t)krow * HD_ + kch);
    vb    = *(const bf16x8*)(vbase + (size_t)krow * HD_ + kch + 8);
    if (tid < 128) cw = ctpb[tid];
    {
        // zero the pad dims 34..39 of every row (both buffers) once — kf2
        // reads them multiplied by Q=0; uninit NaN would poison the MFMA.
        short* pr = &Kt[tid >> 7][tid & 127][34];
        *(unsigned*)(pr) = 0; *(unsigned*)(pr + 2) = 0; *(unsigned*)(pr + 4) = 0;
        // row127/buf0's kf2-hi1 overruns into Kt[1][0][0..8): zero before tile0
        if (tid < 4) *(unsigned*)(&Kt[1][0][tid * 2]) = 0;

        *(bf16x8*)(&Kt[0][krow][kch])     = kreg0;
        *(bf16x8*)(&Kt[0][krow][kch + 8]) = kreg1;
#pragma unroll
        for (int i = 0; i < 8; i++) {
            int d0 = kch + i, d1 = kch + 8 + i;
            Vt[0][d0][((((vc - 2 * (d0 & 7)) & 7) | (vc & 8)) << 3) + vk7] = va[i];
            Vt[0][d1][((((vc - 2 * (d1 & 7)) & 7) | (vc & 8)) << 3) + vk7] = vb[i];
        }
        if (tid < 128) *(unsigned*)(&Kt[0][tid][32]) = cw;
    }
    __syncthreads();

#pragma unroll 1
    for (int t = 0; t < nt; t++) {
        const int cur = t & 1;
        const int knext = (t + 1) << 7;
        const bool more = (t + 1 < nt);

        // ---- ISSUE next tile's global loads ----
        if (more) {
            kreg0 = *(const bf16x8*)(kbase + (size_t)(knext + krow) * HD_ + kch);
            kreg1 = *(const bf16x8*)(kbase + (size_t)(knext + krow) * HD_ + kch + 8);
            va    = *(const bf16x8*)(vbase + (size_t)(knext + krow) * HD_ + kch);
            vb    = *(const bf16x8*)(vbase + (size_t)(knext + krow) * HD_ + kch + 8);
            if (tid < 128) cw = ctpb[knext + tid];
        }

        // ---- QK^T: 3 MFMAs/subtile; penalty+mask ride dims 32,33 ----
        __builtin_amdgcn_s_setprio(1);
        f32x16 sc[4];
#pragma unroll
        for (int t4 = 0; t4 < 4; t4++) {
            const short* kr = &Kt[cur][t4 * 32 + r31][0];
            bf16x8 kf0 = *(const bf16x8*)(kr + hi8);
            bf16x8 kf1 = *(const bf16x8*)(kr + 16 + hi8);
            bf16x8 kf2 = *(const bf16x8*)(kr + 32 + hi8);
            f32x16 s0 = __builtin_amdgcn_mfma_f32_32x32x16_bf16(kf0, qf0, zc, 0, 0, 0);
            f32x16 s1 = __builtin_amdgcn_mfma_f32_32x32x16_bf16(kf1, qf1, s0, 0, 0, 0);
            sc[t4]    = __builtin_amdgcn_mfma_f32_32x32x16_bf16(kf2, qe,  s1, 0, 0, 0);
        }
        __builtin_amdgcn_s_setprio(0);

        // ---- row max: 4 parallel chains, max3-fusable; lane-local ----
        float mxa[4];
#pragma unroll
        for (int g = 0; g < 4; g++) mxa[g] = -1e30f;
#pragma unroll
        for (int t4 = 0; t4 < 4; t4++)
#pragma unroll
            for (int g = 0; g < 4; g++)
                mxa[g] = fmaxf(fmaxf(fmaxf(mxa[g], sc[t4][g * 4]),
                                     fmaxf(sc[t4][g * 4 + 1], sc[t4][g * 4 + 2])),
                               sc[t4][g * 4 + 3]);
        float pmx = fmaxf(fmaxf(mxa[0], mxa[1]), fmaxf(mxa[2], mxa[3]));

        // ---- defer-max: rare rescale (shfl only inside) ----
        if (!__all(pmx <= m_r + 8.f)) {
            pmx = fmaxf(pmx, __shfl_xor(pmx, 32, 64));
            float mn = fmaxf(m_r, pmx);
            float alpha = exp2f(m_r - mn);
            m_r = mn;
#pragma unroll
            for (int r = 0; r < 16; r++) acc[r] *= alpha;
            acc_l[0] *= alpha;
        }
        // scores are raw; subtract the running max only once it's nonzero
        if (__any(m_r != 0.f)) {
#pragma unroll
            for (int t4 = 0; t4 < 4; t4++)
#pragma unroll
                for (int r = 0; r < 16; r++) sc[t4][r] -= m_r;
        }

        // ---- p = exp2(s), cvt_pk pack + permlane ----
        unsigned pk[4][8];
#pragma unroll
        for (int t4 = 0; t4 < 4; t4++) {
            unsigned U[8];
#pragma unroll
            for (int j = 0; j < 8; j++) {
                float pa = exp2f(sc[t4][2 * j]);
                float pb = exp2f(sc[t4][2 * j + 1]);
                U[j] = cvtpk(pa, pb);
            }
            perm32swap(U[0], U[2]);
            perm32swap(U[1], U[3]);
            perm32swap(U[4], U[6]);
            perm32swap(U[5], U[7]);
            pk[t4][0] = U[0]; pk[t4][1] = U[1]; pk[t4][2] = U[2]; pk[t4][3] = U[3];
            pk[t4][4] = U[4]; pk[t4][5] = U[5]; pk[t4][6] = U[6]; pk[t4][7] = U[7];
        }

        // ---- PV + sum-MFMA ----
        __builtin_amdgcn_s_setprio(1);
#pragma unroll
        for (int t4 = 0; t4 < 4; t4++) {
            union { unsigned u[4]; bf16x8 v8; } pb0, pb1;
            pb0.u[0] = pk[t4][0]; pb0.u[1] = pk[t4][1];
            pb0.u[2] = pk[t4][2]; pb0.u[3] = pk[t4][3];
            pb1.u[0] = pk[t4][4]; pb1.u[1] = pk[t4][5];
            pb1.u[2] = pk[t4][6]; pb1.u[3] = pk[t4][7];
            int c0i = t4 * 4 + hi, c1i = t4 * 4 + 2 + hi;
            bf16x8 vf0 = *(const bf16x8*)(&Vt[cur][r31][(((c0i - d7x2) & 7) | (c0i & 8)) << 3]);
            bf16x8 vf1 = *(const bf16x8*)(&Vt[cur][r31][(((c1i - d7x2) & 7) | (c1i & 8)) << 3]);
            acc   = __builtin_amdgcn_mfma_f32_32x32x16_bf16(vf0, pb0.v8, acc, 0, 0, 0);
            acc_l = __builtin_amdgcn_mfma_f32_32x32x16_bf16(ones, pb0.v8, acc_l, 0, 0, 0);
            acc   = __builtin_amdgcn_mfma_f32_32x32x16_bf16(vf1, pb1.v8, acc, 0, 0, 0);
            acc_l = __builtin_amdgcn_mfma_f32_32x32x16_bf16(ones, pb1.v8, acc_l, 0, 0, 0);
        }
        __builtin_amdgcn_s_setprio(0);

        // ---- WRITE next tile, single barrier ----
        if (more) {
            const int nxt = cur ^ 1;
            *(bf16x8*)(&Kt[nxt][krow][kch])     = kreg0;
            *(bf16x8*)(&Kt[nxt][krow][kch + 8]) = kreg1;
#pragma unroll
            for (int i = 0; i < 8; i++) {
                int d0 = kch + i, d1 = kch + 8 + i;
                Vt[nxt][d0][((((vc - 2 * (d0 & 7)) & 7) | (vc & 8)) << 3) + vk7] = va[i];
                Vt[nxt][d1][((((vc - 2 * (d1 & 7)) & 7) | (vc & 8)) << 3) + vk7] = vb[i];
            }
            if (tid < 128) *(unsigned*)(&Kt[nxt][tid][32]) = cw;
            __syncthreads();
        }
    }

    // epilogue: out[d][q] -> ctx row q; denominator from acc_l[0]
    float inv = 1.f / acc_l[0];
    size_t obase = ((size_t)b * S_ + qrow) * H_ + n * HD_;
#pragma unroll
    for (int g = 0; g < 4; g++)
#pragma unroll
        for (int w = 0; w < 2; w++) {
            unsigned uo = cvtpk(acc[g * 4 + w * 2] * inv, acc[g * 4 + w * 2 + 1] * inv);
            int d = 8 * g + hi4 + 2 * w;
            *(unsigned*)(ctxb + obase + d) = uo;
        }
}

// ---------------------------------------------------------------------------
// FC GEMM + residual + LayerNorm fused (unchanged)
// ---------------------------------------------------------------------------
__global__ __launch_bounds__(256) void fc_ln_mfma_kernel(
    const unsigned short* __restrict__ ctxb, const unsigned short* __restrict__ hb,
    const unsigned short* __restrict__ wf2, const float* __restrict__ fb,
    const float* __restrict__ g, const float* __restrict__ bbias,
    float* __restrict__ out)
{
    const int tid = threadIdx.x, wave = tid >> 6, lane = tid & 63;
    const int l15 = lane & 15, l4 = lane >> 4;
    const int s0 = blockIdx.x * 64, b = blockIdx.y;
    const int arow = s0 + wave * 16 + l15;

    bf16x8 af[8];
#pragma unroll
    for (int kb = 0; kb < 8; kb++)
        af[kb] = *(const bf16x8*)(ctxb + (size_t)((size_t)b * S_ + arow) * H_ + kb * 32 + l4 * 8);

    f32x4 acc[16];
#pragma unroll
    for (int ct = 0; ct < 16; ct++) acc[ct] = (f32x4){0.f, 0.f, 0.f, 0.f};

#pragma unroll 1
    for (int kb = 0; kb < 8; kb++) {
        const unsigned short* wp = wf2 + ((size_t)kb * 256 + l15) * 32 + l4 * 8;
#pragma unroll
        for (int ct = 0; ct < 16; ct++) {
            bf16x8 bfr = *(const bf16x8*)(wp + ct * 512);
            acc[ct] = __builtin_amdgcn_mfma_f32_16x16x32_bf16(af[kb], bfr, acc[ct], 0, 0, 0);
        }
    }

    float fbias[16];
#pragma unroll
    for (int ct = 0; ct < 16; ct++) fbias[ct] = fb[ct * 16 + l15];

#pragma unroll
    for (int r = 0; r < 4; r++) {
        int row = s0 + wave * 16 + l4 * 4 + r;
        size_t ro = ((size_t)b * S_ + row) * CC_;
        float z[16];
        float sum = 0.f;
#pragma unroll
        for (int ct = 0; ct < 16; ct++) {
            float zz = acc[ct][r] + fbias[ct] + bf2f(hb[ro + ct * 16 + l15]);
            z[ct] = zz;
            sum += zz;
        }
#pragma unroll
        for (int off = 1; off < 16; off <<= 1) sum += __shfl_xor(sum, off, 64);
        float mu = sum * (1.f / 256.f);
        float vs = 0.f;
#pragma unroll
        for (int ct = 0; ct < 16; ct++) {
            float d = z[ct] - mu;
            z[ct] = d;
            vs += d * d;
        }
#pragma unroll
        for (int off = 1; off < 16; off <<= 1) vs += __shfl_xor(vs, off, 64);
        float inv = rsqrtf(vs * (1.f / 256.f) + 1e-5f);
#pragma unroll
        for (int ct = 0; ct < 16; ct++) {
            int col = ct * 16 + l15;
            out[ro + col] = z[ct] * inv * g[col] + bbias[col];
        }
    }
}

// ---------------------------------------------------------------------------
extern "C" void kernel_launch(void* const* d_in, const int* in_sizes, int n_in,
                              void* d_out, int out_size, void* d_ws, size_t ws_size,
                              hipStream_t stream)
{
    const float* x      = (const float*)d_in[0];
    const void*  mask   = d_in[1];
    const float* conv_w = (const float*)d_in[2];
    const float* conv_b = (const float*)d_in[3];
    const float* wq     = (const float*)d_in[4];
    const float* bq     = (const float*)d_in[5];
    const float* wk     = (const float*)d_in[6];
    const float* bk     = (const float*)d_in[7];
    const float* wv     = (const float*)d_in[8];
    const float* bv     = (const float*)d_in[9];
    const float* fc_w   = (const float*)d_in[10];
    const float* fc_b   = (const float*)d_in[11];
    const float* ln_g   = (const float*)d_in[12];
    const float* ln_b   = (const float*)d_in[13];
    const float* gamma  = (const float*)d_in[14];
    const float* stdp   = (const float*)d_in[15];

    char* ws = (char*)d_ws;
    const size_t MB = 1024 * 1024;
    unsigned short* hb    = (unsigned short*)(ws);
    unsigned short* qb    = (unsigned short*)(ws + 8 * MB);
    unsigned short* kb    = (unsigned short*)(ws + 16 * MB);
    unsigned short* vb    = (unsigned short*)(ws + 24 * MB);
    unsigned short* ctxb  = (unsigned short*)(ws + 32 * MB);
    unsigned*       ctp   = (unsigned*)(ws + 40 * MB);        // 64 KB packed
    int*            lenv  = (int*)(ws + 40 * MB + 256 * 1024);
    unsigned short* wre2  = (unsigned short*)(ws + 41 * MB);
    unsigned short* wqkv2 = (unsigned short*)(ws + 42 * MB);
    unsigned short* wf2   = (unsigned short*)(ws + 43 * MB);

    prep_kernel<<<1928, 256, 0, stream>>>(conv_w, wq, wk, wv, fc_w, mask,
                                          gamma, stdp, wre2, wqkv2, wf2,
                                          ctp, lenv);
    dim3 g2(S_ / 64, B_);
    front_kernel<<<g2, 256, 0, stream>>>(x, wre2, conv_b, wqkv2, bq, bk, bv,
                                         hb, qb, kb, vb);
    dim3 ag(S_ / 128, NH_, B_);
    attn_mfma_kernel<<<ag, 256, 0, stream>>>(qb, kb, vb, ctp, lenv, ctxb);
    fc_ln_mfma_kernel<<<g2, 256, 0, stream>>>(ctxb, hb, wf2, fc_b, ln_g, ln_b,
                                              (float*)d_out);
}